// Round 6
// baseline (210.254 us; speedup 1.0000x reference)
//
#include <hip/hip_runtime.h>
#include <math.h>

// Problem constants (from reference)
constexpr int L     = 2048;
constexpr int NH    = 96;
constexpr int MLEN  = 150;
constexpr int NAR   = 148;
constexpr float LAM    = 0.001f;
constexpr float CLIP_K = 4.0f;

constexpr int TM     = 64;      // rows per block
constexpr int KM     = 64;      // macro K-tile (2 MFMA sub-steps)
constexpr int MSTEPS = L / KM;  // 32

typedef __attribute__((ext_vector_type(8))) short short8;   // 8 bf16 MFMA A/B frag
typedef __attribute__((ext_vector_type(4))) float floatx4;  // MFMA C/D frag

// fp32 -> bf16 round-to-nearest-even
__device__ inline short f2bf(float f) {
    union { float f; unsigned u; } v; v.f = f;
    unsigned r = v.u + 0x7FFFu + ((v.u >> 16) & 1u);
    return (short)(r >> 16);
}

// Pre-kernel: Wt[n][k] = bf16(W[k][n]); 768 KB -> L2-resident gather.
__global__ __launch_bounds__(256) void wt_kernel(
    const float* __restrict__ W, short* __restrict__ Wt)
{
    int idx = blockIdx.x * 256 + threadIdx.x;   // n*2048 + k
    int n = idx >> 11;
    int k = idx & 2047;
    Wt[idx] = f2bf(W[k * NH + n]);
}

// 512 threads = 8 waves per 64-row tile, full K; 256 blocks (1/CU).
// Wave w: row-group h=w>>1 (16 rows), col-half g=w&1 (48 cols) -> disjoint
// 16x48 output quarter, no cross-wave accumulator reduction.
// A: fp32 staged global->LDS (global_load_lds 16B), double-buffered,
//    16B chunks XOR-swizzled by (row&7) within each 128B half-row.
// B: bf16 Wt staged once per block per K-tile ([n][k], XOR-swizzled).
// Bytes/block/step: A 16 KB + B 12 KB; B global traffic halves vs TM=32.
// MFMA layouts: A[m=lane&15][k=quad*8+j]; B[k=quad*8+j][n=lane&15];
// D col=lane&15, row=quad*4+reg.
__global__ __launch_bounds__(512) void gemm_ar2_kernel(
    const float* __restrict__ x, const short* __restrict__ Wt,
    float* __restrict__ out)
{
    __shared__ float As[2][TM * KM];     // 2 x 16 KB fp32 (reused as Ys later)
    __shared__ short Bs[2][NH * KM];     // 2 x 12 KB bf16
    __shared__ float los[TM], his[TM];

    const int t    = threadIdx.x;
    const int lane = t & 63;
    const int wv   = t >> 6;            // 0..7
    const int h    = wv >> 1;           // row group (16 rows each)
    const int g    = wv & 1;            // col half (48 cols each)
    const int m    = lane & 15;
    const int quad = lane >> 4;
    const int row0 = blockIdx.x * TM;
    const int r    = h * 16 + m;        // local row of this lane's A frag
    const int m7   = m & 7;

    // ---- A staging: 16 instrs, wave w issues i = 2w, 2w+1; chunk c = i*64+lane
    // c -> row=c>>4, ch=c&15; global 16B chunk = (ch&7)^(row&7) in half ch>>3.
    const int cA0 = (wv * 2) * 64 + lane, cA1 = cA0 + 64;
    const int rA0 = cA0 >> 4, chA0 = cA0 & 15;
    const int rA1 = cA1 >> 4, chA1 = cA1 & 15;
    const float* pa0 = x + (size_t)(row0 + rA0) * L
                         + ((chA0 >> 3) * 32 + ((chA0 & 7) ^ (rA0 & 7)) * 4);
    const float* pa1 = x + (size_t)(row0 + rA1) * L
                         + ((chA1 >> 3) * 32 + ((chA1 & 7) ^ (rA1 & 7)) * 4);

    // ---- B staging: 12 instrs, wave w issues i = w (all) and i = 8+w (w<4)
    // c -> n=c>>3, kc=c&7; global chunk = kc^(n&7); 16B chunks (8 bf16).
    const int cB0 = wv * 64 + lane;
    const int cB1 = (8 + wv) * 64 + lane;
    const short* pb0 = Wt + (size_t)(cB0 >> 3) * L + (((cB0 & 7) ^ ((cB0 >> 3) & 7)) * 8);
    const short* pb1 = Wt + (size_t)(cB1 >> 3) * L + (((cB1 & 7) ^ ((cB1 >> 3) & 7)) * 8);

    floatx4 acc[3];
    #pragma unroll
    for (int jj = 0; jj < 3; ++jj) acc[jj] = floatx4{0.f, 0.f, 0.f, 0.f};
    float sum = 0.f, sumsq = 0.f;

    auto stage = [&](int buf, int k0) {
        __builtin_amdgcn_global_load_lds(
            (const __attribute__((address_space(1))) unsigned int*)(pa0 + k0),
            (__attribute__((address_space(3))) unsigned int*)&As[buf][(wv * 2) * 256], 16, 0, 0);
        __builtin_amdgcn_global_load_lds(
            (const __attribute__((address_space(1))) unsigned int*)(pa1 + k0),
            (__attribute__((address_space(3))) unsigned int*)&As[buf][(wv * 2 + 1) * 256], 16, 0, 0);
        __builtin_amdgcn_global_load_lds(
            (const __attribute__((address_space(1))) unsigned int*)(pb0 + k0),
            (__attribute__((address_space(3))) unsigned int*)&Bs[buf][wv * 512], 16, 0, 0);
        if (wv < 4)
            __builtin_amdgcn_global_load_lds(
                (const __attribute__((address_space(1))) unsigned int*)(pb1 + k0),
                (__attribute__((address_space(3))) unsigned int*)&Bs[buf][(8 + wv) * 512], 16, 0, 0);
    };

    stage(0, 0);

    const int pA0 = (2 * quad) ^ m7, pA1 = (2 * quad + 1) ^ m7;

    for (int s = 0; s < MSTEPS; ++s) {
        const int cur = s & 1;
        __syncthreads();                       // buf[cur] staged & visible
        if (s + 1 < MSTEPS) stage(cur ^ 1, (s + 1) * KM);

        #pragma unroll
        for (int ss = 0; ss < 2; ++ss) {
            float4 f0 = *(const float4*)&As[cur][r * KM + ss * 32 + pA0 * 4];
            float4 f1 = *(const float4*)&As[cur][r * KM + ss * 32 + pA1 * 4];

            if (g == 0) {   // g==0 waves: full k-coverage of their 16 rows
                sum  += ((f0.x + f0.y) + (f0.z + f0.w))
                      + ((f1.x + f1.y) + (f1.z + f1.w));
                sumsq = fmaf(f0.x, f0.x, sumsq); sumsq = fmaf(f0.y, f0.y, sumsq);
                sumsq = fmaf(f0.z, f0.z, sumsq); sumsq = fmaf(f0.w, f0.w, sumsq);
                sumsq = fmaf(f1.x, f1.x, sumsq); sumsq = fmaf(f1.y, f1.y, sumsq);
                sumsq = fmaf(f1.z, f1.z, sumsq); sumsq = fmaf(f1.w, f1.w, sumsq);
            }

            short8 af;
            af[0] = f2bf(f0.x); af[1] = f2bf(f0.y); af[2] = f2bf(f0.z); af[3] = f2bf(f0.w);
            af[4] = f2bf(f1.x); af[5] = f2bf(f1.y); af[6] = f2bf(f1.z); af[7] = f2bf(f1.w);

            const int bch = ((ss * 4 + quad) ^ m7) * 8;   // n&7 == m&7
            #pragma unroll
            for (int jj = 0; jj < 3; ++jj) {
                short8 bf = *(const short8*)&Bs[cur][(g * 48 + jj * 16 + m) * KM + bch];
                acc[jj] = __builtin_amdgcn_mfma_f32_16x16x32_bf16(af, bf, acc[jj], 0, 0, 0);
            }
        }
    }

    // --- per-row finalize on g==0 waves (rows h*16..h*16+15) ---
    float a1c = 0.f, a2c = 0.f, last = 0.f, y2i = 0.f, lo = 0.f, hi = 0.f;
    if (g == 0) {
        sum   += __shfl_xor(sum,   16); sum   += __shfl_xor(sum,   32);
        sumsq += __shfl_xor(sumsq, 16); sumsq += __shfl_xor(sumsq, 32);

        const float* ytail = x + (size_t)(row0 + r) * L + (L - MLEN);
        float A11 = 0.f, A22 = 0.f, A12 = 0.f, b1 = 0.f, b2 = 0.f;
        for (int i = quad; i < NAR; i += 4) {
            float p2v = ytail[i];
            float p1v = ytail[i + 1];
            float Yv  = ytail[i + 2];
            A11 = fmaf(p1v, p1v, A11);
            A22 = fmaf(p2v, p2v, A22);
            A12 = fmaf(p1v, p2v, A12);
            b1  = fmaf(p1v, Yv,  b1);
            b2  = fmaf(p2v, Yv,  b2);
        }
        A11 += __shfl_xor(A11, 16); A11 += __shfl_xor(A11, 32);
        A22 += __shfl_xor(A22, 16); A22 += __shfl_xor(A22, 32);
        A12 += __shfl_xor(A12, 16); A12 += __shfl_xor(A12, 32);
        b1  += __shfl_xor(b1,  16); b1  += __shfl_xor(b1,  32);
        b2  += __shfl_xor(b2,  16); b2  += __shfl_xor(b2,  32);

        if (quad == 0) {
            A11 += LAM; A22 += LAM;
            float det = A11 * A22 - A12 * A12;
            a1c = (b1 * A22 - b2 * A12) / det;
            a2c = (A11 * b2 - A12 * b1) / det;
            last = ytail[MLEN - 1];
            y2i  = ytail[MLEN - 2];
            float var  = (sumsq - sum * sum * (1.0f / L)) * (1.0f / (L - 1));
            float hstd = fmaxf(sqrtf(fmaxf(var, 0.f)), 1e-6f);
            lo = last - CLIP_K * hstd;
            hi = last + CLIP_K * hstd;
        }
    }
    __syncthreads();                    // everyone done reading As

    // reuse As storage (32 KB) for Ys[64][97] fp32 (24.8 KB)
    float* YsF = (float*)As;
    if (g == 0 && quad == 0) {          // 64 lanes total: one row each
        float y1 = last, y2 = y2i;
        for (int n = 0; n < NH; ++n) {
            float yn = a1c * y1 + a2c * y2;
            YsF[r * (NH + 1) + n] = yn;
            y2 = y1; y1 = yn;
        }
        los[r] = lo;
        his[r] = hi;
    }
    __syncthreads();

    // --- epilogue: each wave stores its disjoint 16x48 quarter ---
    #pragma unroll
    for (int reg = 0; reg < 4; ++reg) {
        int rl = h * 16 + quad * 4 + reg;
        float rlo = los[rl], rhi = his[rl];
        #pragma unroll
        for (int jj = 0; jj < 3; ++jj) {
            int c = (3 * g + jj) * 16 + m;
            float v = acc[jj][reg] + YsF[rl * (NH + 1) + c];
            v = fminf(fmaxf(v, rlo), rhi);
            out[(size_t)(row0 + rl) * NH + c] = v;
        }
    }
}

extern "C" void kernel_launch(void* const* d_in, const int* in_sizes, int n_in,
                              void* d_out, int out_size, void* d_ws, size_t ws_size,
                              hipStream_t stream) {
    const float* x = (const float*)d_in[0];   // (32,512,2048) fp32
    const float* W = (const float*)d_in[1];   // (2048,96) fp32
    float* out = (float*)d_out;               // (32,512,96) fp32
    short* Wt  = (short*)d_ws;                // 96*2048 bf16 = 384 KB scratch

    wt_kernel<<<dim3((NH * L) / 256), dim3(256), 0, stream>>>(W, Wt);

    const int rows = 32 * 512;                // 16384
    gemm_ar2_kernel<<<dim3(rows / TM), dim3(512), 0, stream>>>(x, Wt, out);
}

// Round 7
// 208.056 us; speedup vs baseline: 1.0106x; 1.0106x over previous
//
#include <hip/hip_runtime.h>
#include <math.h>

// Problem constants (from reference)
constexpr int L     = 2048;
constexpr int NH    = 96;
constexpr int MLEN  = 150;
constexpr int NAR   = 148;
constexpr float LAM    = 0.001f;
constexpr float CLIP_K = 4.0f;

constexpr int TM     = 32;      // rows per block
constexpr int KM     = 64;      // K per phase (2 MFMA sub-steps)
constexpr int MSTEPS = L / KM;  // 32 phases

typedef __attribute__((ext_vector_type(8))) short short8;   // 8 bf16 MFMA A/B frag
typedef __attribute__((ext_vector_type(4))) float floatx4;  // MFMA C/D frag

// fp32 -> bf16 round-to-nearest-even
__device__ inline short f2bf(float f) {
    union { float f; unsigned u; } v; v.f = f;
    unsigned r = v.u + 0x7FFFu + ((v.u >> 16) & 1u);
    return (short)(r >> 16);
}

// Pre-kernel: Wt[n][k] = bf16(W[k][n]); 768 KB -> L2-resident gather.
__global__ __launch_bounds__(256) void wt_kernel(
    const float* __restrict__ W, short* __restrict__ Wt)
{
    int idx = blockIdx.x * 256 + threadIdx.x;   // n*2048 + k
    int n = idx >> 11;
    int k = idx & 2047;
    Wt[idx] = f2bf(W[k * NH + n]);
}

// 256 threads = 4 waves per 32-row tile, full K; grid 512 (2 blocks/CU).
// Wave w: row-half h=w>>1 (16 rows), col-half g=w&1 (48 cols) -> disjoint
// 16x48 output quarter.
// TRIPLE-buffered global_load_lds staging; K-loop uses RAW asm
//   s_waitcnt vmcnt(5); s_barrier
// instead of __syncthreads() -> no vmcnt(0) drain; prefetch distance = 2
// phases. Every wave issues exactly 5 staging loads per phase (2 A + 3 B),
// so vmcnt(5) == "oldest phase complete, newest still in flight".
// A fp32 [row][k], 16B chunks XOR-swizzled by (row&7) within 8-chunk halves.
// B bf16 [n][k], 16B chunks XOR-swizzled by (n&7).
// MFMA layouts: A[m=lane&15][k=quad*8+j]; B[k=quad*8+j][n=lane&15];
// D col=lane&15, row=quad*4+reg.
__global__ __launch_bounds__(256) void gemm_ar2_kernel(
    const float* __restrict__ x, const short* __restrict__ Wt,
    float* __restrict__ out)
{
    __shared__ float As[3][TM * KM];     // 3 x 8 KB fp32
    __shared__ short Bs[3][NH * KM];     // 3 x 12 KB bf16 (reused as Ys later)
    __shared__ float los[TM], his[TM];

    const int t    = threadIdx.x;
    const int lane = t & 63;
    const int wv   = t >> 6;            // 0..3
    const int h    = wv >> 1;           // row half
    const int g    = wv & 1;            // col half
    const int m    = lane & 15;
    const int quad = lane >> 4;
    const int row0 = blockIdx.x * TM;
    const int r    = h * 16 + m;        // local row of this lane's A frag
    const int m7   = m & 7;

    // ---- A staging: 8 instrs/block, wave issues i = 2wv+{0,1}.
    // flat chunk f = i*64+lane: row = f>>4, c = f&15;
    // global chunk = (c&8) | ((c ^ (row&7)) & 7); 16B chunks (4 floats).
    const float* paSrc[2];
    int aDst[2];
    #pragma unroll
    for (int u = 0; u < 2; ++u) {
        int i  = wv * 2 + u;
        int rr = i * 4 + (lane >> 4);
        int c  = lane & 15;
        int gg = (c & 8) | ((c ^ (rr & 7)) & 7);
        paSrc[u] = x + (size_t)(row0 + rr) * L + gg * 4;
        aDst[u]  = i * 256;             // floats (1 KB per instr)
    }

    // ---- B staging: 12 instrs/block, wave issues i = 3wv+{0,1,2}.
    // flat chunk f = i*64+lane: n = f>>3, c = f&7;
    // global chunk = (c ^ (n&7)) & 7; 16B chunks (8 bf16).
    const short* pbSrc[3];
    int bDst[3];
    #pragma unroll
    for (int u = 0; u < 3; ++u) {
        int i  = wv * 3 + u;
        int nn = i * 8 + (lane >> 3);
        int c  = lane & 7;
        int gg = (c ^ (nn & 7)) & 7;
        pbSrc[u] = Wt + (size_t)nn * L + gg * 8;
        bDst[u]  = i * 512;             // shorts (1 KB per instr)
    }

    auto stage = [&](int buf, int k0) {
        #pragma unroll
        for (int u = 0; u < 2; ++u)
            __builtin_amdgcn_global_load_lds(
                (const __attribute__((address_space(1))) unsigned int*)(paSrc[u] + k0),
                (__attribute__((address_space(3))) unsigned int*)&As[buf][aDst[u]], 16, 0, 0);
        #pragma unroll
        for (int u = 0; u < 3; ++u)
            __builtin_amdgcn_global_load_lds(
                (const __attribute__((address_space(1))) unsigned int*)(pbSrc[u] + k0),
                (__attribute__((address_space(3))) unsigned int*)&Bs[buf][bDst[u]], 16, 0, 0);
    };

    floatx4 acc[3];
    #pragma unroll
    for (int jj = 0; jj < 3; ++jj) acc[jj] = floatx4{0.f, 0.f, 0.f, 0.f};
    float sum = 0.f, sumsq = 0.f;

    // prologue: two tiles in flight, wait for tile 0 only
    stage(0, 0);
    stage(1, KM);
    asm volatile("s_waitcnt vmcnt(5)\n\ts_barrier" ::: "memory");

    int buf = 0;
    for (int s = 0; s < MSTEPS; ++s) {
        // issue tile s+2 (clamped dummy re-stage in the tail keeps the
        // per-wave vm-op count uniform; target buffer is always the one
        // consumed at phase s-1, so the garbage is harmless)
        const int nb = (buf + 2 >= 3) ? (buf + 2 - 3) : (buf + 2);
        const int k2 = ((s + 2 < MSTEPS) ? (s + 2) : (MSTEPS - 1)) * KM;
        stage(nb, k2);

        const float* Ab = &As[buf][0];
        const short* Bb = &Bs[buf][0];

        #pragma unroll
        for (int ss = 0; ss < 2; ++ss) {
            const int ch0 = ss * 8 + 2 * quad;
            const int p0  = (ch0 & 8) | ((ch0 ^ m7) & 7);
            const int p1  = ((ch0 + 1) & 8) | (((ch0 + 1) ^ m7) & 7);
            float4 f0 = *(const float4*)&Ab[r * KM + p0 * 4];
            float4 f1 = *(const float4*)&Ab[r * KM + p1 * 4];

            if (g == 0) {   // g==0 waves: full k-coverage of their 16 rows
                sum  += ((f0.x + f0.y) + (f0.z + f0.w))
                      + ((f1.x + f1.y) + (f1.z + f1.w));
                sumsq = fmaf(f0.x, f0.x, sumsq); sumsq = fmaf(f0.y, f0.y, sumsq);
                sumsq = fmaf(f0.z, f0.z, sumsq); sumsq = fmaf(f0.w, f0.w, sumsq);
                sumsq = fmaf(f1.x, f1.x, sumsq); sumsq = fmaf(f1.y, f1.y, sumsq);
                sumsq = fmaf(f1.z, f1.z, sumsq); sumsq = fmaf(f1.w, f1.w, sumsq);
            }

            short8 af;
            af[0] = f2bf(f0.x); af[1] = f2bf(f0.y); af[2] = f2bf(f0.z); af[3] = f2bf(f0.w);
            af[4] = f2bf(f1.x); af[5] = f2bf(f1.y); af[6] = f2bf(f1.z); af[7] = f2bf(f1.w);

            const int pb = ((ss * 4 + quad) ^ m7) & 7;
            #pragma unroll
            for (int jj = 0; jj < 3; ++jj) {
                short8 bf = *(const short8*)&Bb[(g * 48 + jj * 16 + m) * KM + pb * 8];
                acc[jj] = __builtin_amdgcn_mfma_f32_16x16x32_bf16(af, bf, acc[jj], 0, 0, 0);
            }
        }

        // tile s+1 must be complete; tile s+2 stays in flight
        asm volatile("s_waitcnt vmcnt(5)\n\ts_barrier" ::: "memory");
        buf = (buf + 1 >= 3) ? 0 : (buf + 1);
    }

    __syncthreads();    // drain dummy stages; safe to reuse LDS

    // --- per-row finalize on g==0 waves (rows h*16..h*16+15) ---
    float a1c = 0.f, a2c = 0.f, last = 0.f, y2i = 0.f, lo = 0.f, hi = 0.f;
    if (g == 0) {
        sum   += __shfl_xor(sum,   16); sum   += __shfl_xor(sum,   32);
        sumsq += __shfl_xor(sumsq, 16); sumsq += __shfl_xor(sumsq, 32);

        const float* ytail = x + (size_t)(row0 + r) * L + (L - MLEN);
        float A11 = 0.f, A22 = 0.f, A12 = 0.f, b1 = 0.f, b2 = 0.f;
        for (int i = quad; i < NAR; i += 4) {
            float p2v = ytail[i];
            float p1v = ytail[i + 1];
            float Yv  = ytail[i + 2];
            A11 = fmaf(p1v, p1v, A11);
            A22 = fmaf(p2v, p2v, A22);
            A12 = fmaf(p1v, p2v, A12);
            b1  = fmaf(p1v, Yv,  b1);
            b2  = fmaf(p2v, Yv,  b2);
        }
        A11 += __shfl_xor(A11, 16); A11 += __shfl_xor(A11, 32);
        A22 += __shfl_xor(A22, 16); A22 += __shfl_xor(A22, 32);
        A12 += __shfl_xor(A12, 16); A12 += __shfl_xor(A12, 32);
        b1  += __shfl_xor(b1,  16); b1  += __shfl_xor(b1,  32);
        b2  += __shfl_xor(b2,  16); b2  += __shfl_xor(b2,  32);

        if (quad == 0) {
            A11 += LAM; A22 += LAM;
            float det = A11 * A22 - A12 * A12;
            a1c = (b1 * A22 - b2 * A12) / det;
            a2c = (A11 * b2 - A12 * b1) / det;
            last = ytail[MLEN - 1];
            y2i  = ytail[MLEN - 2];
            float var  = (sumsq - sum * sum * (1.0f / L)) * (1.0f / (L - 1));
            float hstd = fmaxf(sqrtf(fmaxf(var, 0.f)), 1e-6f);
            lo = last - CLIP_K * hstd;
            hi = last + CLIP_K * hstd;
        }
    }

    // reuse Bs storage (36 KB) for Ys[32][97] fp32 (12.4 KB)
    float* YsF = (float*)Bs;
    if (g == 0 && quad == 0) {          // 32 lanes total: one row each
        float y1 = last, y2 = y2i;
        for (int n = 0; n < NH; ++n) {
            float yn = a1c * y1 + a2c * y2;
            YsF[r * (NH + 1) + n] = yn;
            y2 = y1; y1 = yn;
        }
        los[r] = lo;
        his[r] = hi;
    }
    __syncthreads();

    // --- epilogue: each wave stores its disjoint 16x48 quarter ---
    #pragma unroll
    for (int reg = 0; reg < 4; ++reg) {
        int rl = h * 16 + quad * 4 + reg;
        float rlo = los[rl], rhi = his[rl];
        #pragma unroll
        for (int jj = 0; jj < 3; ++jj) {
            int c = (3 * g + jj) * 16 + m;
            float v = acc[jj][reg] + YsF[rl * (NH + 1) + c];
            v = fminf(fmaxf(v, rlo), rhi);
            out[(size_t)(row0 + rl) * NH + c] = v;
        }
    }
}

extern "C" void kernel_launch(void* const* d_in, const int* in_sizes, int n_in,
                              void* d_out, int out_size, void* d_ws, size_t ws_size,
                              hipStream_t stream) {
    const float* x = (const float*)d_in[0];   // (32,512,2048) fp32
    const float* W = (const float*)d_in[1];   // (2048,96) fp32
    float* out = (float*)d_out;               // (32,512,96) fp32
    short* Wt  = (short*)d_ws;                // 96*2048 bf16 = 384 KB scratch

    wt_kernel<<<dim3((NH * L) / 256), dim3(256), 0, stream>>>(W, Wt);

    const int rows = 32 * 512;                // 16384
    gemm_ar2_kernel<<<dim3(rows / TM), dim3(256), 0, stream>>>(x, Wt, out);
}